// Round 1
// baseline (565.231 us; speedup 1.0000x reference)
//
#include <hip/hip_runtime.h>
#include <hip/hip_bf16.h>
#include <stdint.h>

typedef __bf16 bf16;
typedef __bf16 bf16x8 __attribute__((ext_vector_type(8)));
typedef __bf16 bf16x4 __attribute__((ext_vector_type(4)));
typedef float f32x4 __attribute__((ext_vector_type(4)));

#define B_ 2
#define L_ 2048
#define E_ 2048
#define H_ 16
#define HKV_ 2
#define G_ 8
#define D_ 128
#define SPAST_ 2048
#define S_ 4096
#define EKV_ 256

#define MFMA16(a, b, c) __builtin_amdgcn_mfma_f32_16x16x32_bf16(a, b, c, 0, 0, 0)

__device__ __forceinline__ void gload16(const bf16* g, bf16* l) {
  __builtin_amdgcn_global_load_lds(
      (__attribute__((address_space(1))) void*)g,
      (__attribute__((address_space(3))) void*)l, 16, 0, 0);
}

// ---------------- f32 -> bf16 conversion ----------------
__global__ void cvt_kernel(const float* __restrict__ src, bf16* __restrict__ dst, int n) {
  int i = (blockIdx.x * 256 + threadIdx.x) * 4;
  if (i >= n) return;
  float4 v = *(const float4*)(src + i);
  bf16x4 o;
  o[0] = (bf16)v.x; o[1] = (bf16)v.y; o[2] = (bf16)v.z; o[3] = (bf16)v.w;
  *(bf16x4*)(dst + i) = o;
}

// ---------------- trig table: trig[l*64+j] = {cos, sin}((offset+l) * 10000^(-j/64)) ----------------
__global__ void trig_kernel(const int* __restrict__ offp, float2* __restrict__ trig) {
  int l = blockIdx.x, j = threadIdx.x;  // 64 threads
  float inv = exp2f(-(float)j * (13.287712379549449f / 64.0f));  // log2(10000)
  float ang = (float)(*offp + l) * inv;
  trig[l * 64 + j] = make_float2(cosf(ang), sinf(ang));
}

// ---------------- NT GEMM: C(M,N) = A(M,K) @ Bw(N,K)^T + bias ----------------
// 128x128 tile, BK=64, 4 waves (2x2), 16x16x32 MFMA, global_load_lds w/ XOR swizzle.
template <int OUTF32>
__global__ __launch_bounds__(256) void gemm_nt(const bf16* __restrict__ A,
                                               const bf16* __restrict__ Bw,
                                               const float* __restrict__ bias,
                                               void* __restrict__ Cout,
                                               int M, int N, int K) {
  __shared__ bf16 As[128 * 64];
  __shared__ bf16 Bs[128 * 64];
  const int tid = threadIdx.x;
  const int wid = tid >> 6, lane = tid & 63;
  const int ln15 = lane & 15, lq = lane >> 4;
  const int row0 = blockIdx.x * 128, col0 = blockIdx.y * 128;
  const int wr = wid >> 1, wc = wid & 1;
  f32x4 acc[4][4] = {};
  char* AsB = (char*)As;
  char* BsB = (char*)Bs;
  for (int k0 = 0; k0 < K; k0 += 64) {
    // stage: 1024 chunks of 16B each for A and B; linear LDS, source pre-swizzled
#pragma unroll
    for (int j = 0; j < 4; j++) {
      int cid = j * 256 + tid;
      int r = cid >> 3, c = cid & 7;
      int csw = (c ^ (r & 7)) << 3;
      gload16(A + (size_t)(row0 + r) * K + k0 + csw, (bf16*)(AsB + (j * 256 + wid * 64) * 16));
      gload16(Bw + (size_t)(col0 + r) * K + k0 + csw, (bf16*)(BsB + (j * 256 + wid * 64) * 16));
    }
    __syncthreads();
    bf16x8 af[4][2], bfm[4][2];
#pragma unroll
    for (int m = 0; m < 4; m++) {
#pragma unroll
      for (int kk = 0; kk < 2; kk++) {
        int Ra = wr * 64 + m * 16 + ln15;
        int Rb = wc * 64 + m * 16 + ln15;
        int c = (kk << 2) + lq;
        af[m][kk] = *(const bf16x8*)(AsB + Ra * 128 + ((c ^ (Ra & 7)) << 4));
        bfm[m][kk] = *(const bf16x8*)(BsB + Rb * 128 + ((c ^ (Rb & 7)) << 4));
      }
    }
#pragma unroll
    for (int m = 0; m < 4; m++)
#pragma unroll
      for (int n = 0; n < 4; n++)
#pragma unroll
        for (int kk = 0; kk < 2; kk++)
          acc[m][n] = MFMA16(af[m][kk], bfm[n][kk], acc[m][n]);
    __syncthreads();
  }
  // epilogue: C/D layout col=lane&15, row=4*(lane>>4)+reg
#pragma unroll
  for (int m = 0; m < 4; m++) {
    int gr0 = row0 + wr * 64 + m * 16 + 4 * lq;
#pragma unroll
    for (int n = 0; n < 4; n++) {
      int gc = col0 + wc * 64 + n * 16 + ln15;
      float bv = bias ? bias[gc] : 0.0f;
#pragma unroll
      for (int reg = 0; reg < 4; reg++) {
        float v = acc[m][n][reg] + bv;
        size_t idx = (size_t)(gr0 + reg) * N + gc;
        if (OUTF32)
          ((float*)Cout)[idx] = v;
        else
          ((bf16*)Cout)[idx] = (bf16)v;
      }
    }
  }
}

// ---------------- RoPE on Q, scatter to (B,H,L,D), fold softmax scale*log2e ----------------
__global__ void rope_q_kernel(const bf16* __restrict__ q_lin, const float2* __restrict__ trig,
                              bf16* __restrict__ qbuf) {
  int bl = blockIdx.x;
  int b = bl >> 11, l = bl & 2047;  // L=2048
  const float QS = 0.08838834764831845f * 1.4426950408889634f;  // 1/sqrt(128) * log2(e)
  for (int i = threadIdx.x; i < H_ * 64; i += 256) {
    int h = i >> 6, j = i & 63;
    float2 cs = trig[l * 64 + j];
    float x1 = (float)q_lin[(size_t)bl * E_ + h * D_ + j];
    float x2 = (float)q_lin[(size_t)bl * E_ + h * D_ + 64 + j];
    size_t o = ((size_t)(b * H_ + h) * L_ + l) * D_ + j;
    qbuf[o] = (bf16)((x1 * cs.x - x2 * cs.y) * QS);
    qbuf[o + 64] = (bf16)((x2 * cs.x + x1 * cs.y) * QS);
  }
}

// ---------------- build k_all (B,HKV,S,D): cache ++ rope(new K) ----------------
__global__ void build_k_kernel(const float* __restrict__ k_cache, const bf16* __restrict__ k_lin,
                               const float2* __restrict__ trig, bf16* __restrict__ k_all) {
  int d = threadIdx.x;  // 128
  int s = blockIdx.x;
  int bz = blockIdx.y;  // b*HKV + hkv
  size_t oidx = ((size_t)bz * S_ + s) * D_ + d;
  if (s < SPAST_) {
    k_all[oidx] = (bf16)k_cache[((size_t)bz * SPAST_ + s) * D_ + d];
  } else {
    int l = s - SPAST_;
    int b = bz >> 1, kh = bz & 1;
    int j = d & 63;
    float2 cs = trig[l * 64 + j];
    size_t base = (size_t)(b * L_ + l) * EKV_ + kh * D_;
    float x1 = (float)k_lin[base + j];
    float x2 = (float)k_lin[base + 64 + j];
    float v = (d < 64) ? (x1 * cs.x - x2 * cs.y) : (x2 * cs.x + x1 * cs.y);
    k_all[oidx] = (bf16)v;
  }
}

// ---------------- build transposed V: vtall (B,HKV,D,S) ----------------
__global__ void build_vt_kernel(const float* __restrict__ v_cache, const bf16* __restrict__ v_lin,
                                bf16* __restrict__ vtall) {
  __shared__ float tile[64][65];
  int s0 = blockIdx.x * 64;
  int d0 = blockIdx.y * 64;
  int bz = blockIdx.z;
  int b = bz >> 1, kh = bz & 1;
  for (int i = threadIdx.x; i < 4096; i += 256) {
    int ss = i >> 6, dd = i & 63;
    int s = s0 + ss;
    float v;
    if (s < SPAST_)
      v = v_cache[((size_t)bz * SPAST_ + s) * D_ + d0 + dd];
    else
      v = (float)v_lin[(size_t)(b * L_ + (s - SPAST_)) * EKV_ + kh * D_ + d0 + dd];
    tile[ss][dd] = v;
  }
  __syncthreads();
  for (int i = threadIdx.x; i < 4096; i += 256) {
    int dd = i >> 6, ss = i & 63;
    vtall[((size_t)bz * D_ + d0 + dd) * S_ + s0 + ss] = (bf16)tile[ss][dd];
  }
}

// ---------------- flash attention ----------------
// grid (L/64, B*H); 4 waves, 16 query rows each; 64-key chunks.
__global__ __launch_bounds__(256) void attn_kernel(const bf16* __restrict__ qbuf,
                                                   const bf16* __restrict__ k_all,
                                                   const bf16* __restrict__ vtall,
                                                   bf16* __restrict__ attnout) {
  __shared__ bf16 Ks[64 * 128];      // [key][d] 256B rows
  __shared__ bf16 Vs[128 * 64];      // [d][key] 128B rows
  __shared__ bf16 Ps[4 * 16 * 72];   // per-wave P, 144B rows (bank-clean pad)
  const int tid = threadIdx.x;
  const int wid = tid >> 6, lane = tid & 63;
  const int ln15 = lane & 15, lq = lane >> 4;
  const int q0 = blockIdx.x * 64;
  const int bh = blockIdx.y;
  const int b = bh / H_, h = bh % H_;
  const int hkv = h / G_;
  const bf16* kb = k_all + (size_t)(b * HKV_ + hkv) * S_ * D_;
  const bf16* vb = vtall + (size_t)(b * HKV_ + hkv) * D_ * S_;
  // Q fragments: A row = lane&15, k = 8*(lane>>4)+i
  bf16x8 qf[4];
  {
    int q = q0 + wid * 16 + ln15;
    const bf16* qp = qbuf + ((size_t)(b * H_ + h) * L_ + q) * D_ + lq * 8;
#pragma unroll
    for (int kk = 0; kk < 4; kk++) qf[kk] = *(const bf16x8*)(qp + kk * 32);
  }
  f32x4 acc[8] = {};
  float mrun[4] = {-3e38f, -3e38f, -3e38f, -3e38f};
  float lrun[4] = {0.f, 0.f, 0.f, 0.f};
  char* KsB = (char*)Ks;
  char* VsB = (char*)Vs;
  char* PsB = (char*)Ps + wid * (16 * 144);
  int smax = q0 + 64 + SPAST_;
  if (smax > S_) smax = S_;
  const int nchunk = smax >> 6;
  for (int sc = 0; sc < nchunk; ++sc) {
    int s0 = sc * 64;
#pragma unroll
    for (int j = 0; j < 4; j++) {
      int cid = j * 256 + tid;
      {  // K chunk: 64 rows x 16 chunks
        int r = cid >> 4, c = cid & 15;
        gload16(kb + (size_t)(s0 + r) * D_ + ((c ^ (r & 7)) << 3),
                (bf16*)(KsB + (j * 256 + wid * 64) * 16));
      }
      {  // V^T chunk: 128 rows x 8 chunks
        int r = cid >> 3, c = cid & 7;
        gload16(vb + (size_t)r * S_ + s0 + ((c ^ (r & 7)) << 3),
                (bf16*)(VsB + (j * 256 + wid * 64) * 16));
      }
    }
    __syncthreads();
    // QK^T: scores tile per kt: D col=key(lane&15), row=q(4*lq+reg)
    f32x4 sc4[4];
#pragma unroll
    for (int kt = 0; kt < 4; kt++) {
      f32x4 a = {};
      int R = kt * 16 + ln15;
#pragma unroll
      for (int kk = 0; kk < 4; kk++) {
        int c = (kk << 2) + lq;
        bf16x8 kf = *(const bf16x8*)(KsB + R * 256 + ((c ^ (R & 7)) << 4));
        a = MFMA16(qf[kk], kf, a);
      }
      sc4[kt] = a;
    }
    // causal mask: key > q + (S-L) -> -inf
    int qg = q0 + wid * 16 + 4 * lq;
#pragma unroll
    for (int kt = 0; kt < 4; kt++) {
      int key = s0 + kt * 16 + ln15;
#pragma unroll
      for (int reg = 0; reg < 4; reg++)
        if (key > qg + reg + SPAST_) sc4[kt][reg] = -1e30f;
    }
    // online softmax (scores already in log2 units)
    float fac[4];
#pragma unroll
    for (int reg = 0; reg < 4; reg++) {
      float mx = fmaxf(fmaxf(sc4[0][reg], sc4[1][reg]), fmaxf(sc4[2][reg], sc4[3][reg]));
#pragma unroll
      for (int off = 1; off < 16; off <<= 1) mx = fmaxf(mx, __shfl_xor(mx, off));
      float mnew = fmaxf(mrun[reg], mx);
      fac[reg] = exp2f(mrun[reg] - mnew);
      mrun[reg] = mnew;
    }
    float rs[4] = {0.f, 0.f, 0.f, 0.f};
#pragma unroll
    for (int kt = 0; kt < 4; kt++)
#pragma unroll
      for (int reg = 0; reg < 4; reg++) {
        float p = exp2f(sc4[kt][reg] - mrun[reg]);
        sc4[kt][reg] = p;
        rs[reg] += p;
      }
#pragma unroll
    for (int reg = 0; reg < 4; reg++) {
#pragma unroll
      for (int off = 1; off < 16; off <<= 1) rs[reg] += __shfl_xor(rs[reg], off);
      lrun[reg] = lrun[reg] * fac[reg] + rs[reg];
    }
#pragma unroll
    for (int dt = 0; dt < 8; dt++)
#pragma unroll
      for (int reg = 0; reg < 4; reg++) acc[dt][reg] *= fac[reg];
    // P -> LDS (wave-local), re-layout scores -> A operand
#pragma unroll
    for (int kt = 0; kt < 4; kt++)
#pragma unroll
      for (int reg = 0; reg < 4; reg++)
        *(bf16*)(PsB + (4 * lq + reg) * 144 + (kt * 16 + ln15) * 2) = (bf16)sc4[kt][reg];
    bf16x8 pa[2];
#pragma unroll
    for (int kc = 0; kc < 2; kc++)
      pa[kc] = *(const bf16x8*)(PsB + ln15 * 144 + ((kc * 4 + lq) << 4));
    // PV: B operand from V^T rows (d), k-contiguous keys
#pragma unroll
    for (int dt = 0; dt < 8; dt++) {
      int R = dt * 16 + ln15;
#pragma unroll
      for (int kc = 0; kc < 2; kc++) {
        int c = (kc << 2) + lq;
        bf16x8 vf = *(const bf16x8*)(VsB + R * 128 + ((c ^ (R & 7)) << 4));
        acc[dt] = MFMA16(pa[kc], vf, acc[dt]);
      }
    }
    __syncthreads();
  }
  // epilogue: attnout (B, L, H*D)
  int qg = q0 + wid * 16 + 4 * lq;
#pragma unroll
  for (int reg = 0; reg < 4; reg++) {
    float inv = 1.0f / lrun[reg];
    size_t base = ((size_t)(b * L_ + qg + reg) * H_ + h) * D_;
#pragma unroll
    for (int dt = 0; dt < 8; dt++)
      attnout[base + dt * 16 + ln15] = (bf16)(acc[dt][reg] * inv);
  }
}

extern "C" void kernel_launch(void* const* d_in, const int* in_sizes, int n_in,
                              void* d_out, int out_size, void* d_ws, size_t ws_size,
                              hipStream_t stream) {
  const float* x = (const float*)d_in[0];
  const float* wq = (const float*)d_in[1];
  const float* wk = (const float*)d_in[2];
  const float* wv = (const float*)d_in[3];
  const float* wo = (const float*)d_in[4];
  const float* bq = (const float*)d_in[5];
  const float* bk = (const float*)d_in[6];
  const float* bv = (const float*)d_in[7];
  const float* k_cache = (const float*)d_in[8];
  const float* v_cache = (const float*)d_in[9];
  const int* offp = (const int*)d_in[10];

  char* w = (char*)d_ws;
  size_t off = 0;
  auto alloc = [&](size_t bytes) -> char* {
    char* p = w + off;
    off += (bytes + 255) & ~(size_t)255;
    return p;
  };
  const size_t nBLE = (size_t)B_ * L_ * E_;       // 8388608
  const size_t nBLKV = (size_t)B_ * L_ * EKV_;    // 1048576
  const size_t nKV = (size_t)B_ * HKV_ * S_ * D_; // 2097152
  bf16* xb = (bf16*)alloc(nBLE * 2);
  bf16* wqb = (bf16*)alloc((size_t)E_ * E_ * 2);
  bf16* wkb = (bf16*)alloc((size_t)EKV_ * E_ * 2);
  bf16* wvb = (bf16*)alloc((size_t)EKV_ * E_ * 2);
  bf16* wob = (bf16*)alloc((size_t)E_ * E_ * 2);
  bf16* q_lin = (bf16*)alloc(nBLE * 2);
  bf16* k_lin = (bf16*)alloc(nBLKV * 2);
  bf16* v_lin = (bf16*)alloc(nBLKV * 2);
  bf16* qbuf = (bf16*)alloc(nBLE * 2);
  bf16* k_all = (bf16*)alloc(nKV * 2);
  bf16* vtall = (bf16*)alloc(nKV * 2);
  bf16* attnout = (bf16*)alloc(nBLE * 2);
  float2* trig = (float2*)alloc((size_t)L_ * 64 * sizeof(float2));

  // conversions
  cvt_kernel<<<(int)(nBLE / 1024), 256, 0, stream>>>(x, xb, (int)nBLE);
  cvt_kernel<<<(int)((size_t)E_ * E_ / 1024), 256, 0, stream>>>(wq, wqb, E_ * E_);
  cvt_kernel<<<(int)((size_t)EKV_ * E_ / 1024), 256, 0, stream>>>(wk, wkb, EKV_ * E_);
  cvt_kernel<<<(int)((size_t)EKV_ * E_ / 1024), 256, 0, stream>>>(wv, wvb, EKV_ * E_);
  cvt_kernel<<<(int)((size_t)E_ * E_ / 1024), 256, 0, stream>>>(wo, wob, E_ * E_);
  trig_kernel<<<L_, 64, 0, stream>>>(offp, trig);

  const int M = B_ * L_;  // 4096
  // projections
  gemm_nt<0><<<dim3(M / 128, E_ / 128), 256, 0, stream>>>(xb, wqb, bq, q_lin, M, E_, E_);
  gemm_nt<0><<<dim3(M / 128, EKV_ / 128), 256, 0, stream>>>(xb, wkb, bk, k_lin, M, EKV_, E_);
  gemm_nt<0><<<dim3(M / 128, EKV_ / 128), 256, 0, stream>>>(xb, wvb, bv, v_lin, M, EKV_, E_);
  // rope + KV assembly
  rope_q_kernel<<<B_ * L_, 256, 0, stream>>>(q_lin, trig, qbuf);
  build_k_kernel<<<dim3(S_, B_ * HKV_), 128, 0, stream>>>(k_cache, k_lin, trig, k_all);
  build_vt_kernel<<<dim3(S_ / 64, D_ / 64, B_ * HKV_), 256, 0, stream>>>(v_cache, v_lin, vtall);
  // attention
  attn_kernel<<<dim3(L_ / 64, B_ * H_), 256, 0, stream>>>(qbuf, k_all, vtall, attnout);
  // output projection -> f32 d_out
  gemm_nt<1><<<dim3(M / 128, E_ / 128), 256, 0, stream>>>(attnout, wob, nullptr, d_out, M, E_, E_);
}